// Round 8
// baseline (885.580 us; speedup 1.0000x reference)
//
#include <hip/hip_runtime.h>
#include <hip/hip_bf16.h>

#define N_NODES 50000
#define N_EDGES 500000
#define NBLK_E  1024

// scales
#define S32        0.17677669529663687f   // 1/sqrt(32)
#define INV_SQRT3  0.5773502691896258f
#define WSCALE     0.03952847075210474f   // (1/8 from /sqrt(64)) * (1/sqrt(10))

typedef __attribute__((ext_vector_type(8))) short bf16x8;
typedef __attribute__((ext_vector_type(4))) float f32x4;

static __device__ __forceinline__ unsigned short f2bf(float x) {
    __hip_bfloat16 b = __float2bfloat16(x);
    union { __hip_bfloat16 b; unsigned short u; } cv; cv.b = b; return cv.u;
}
static __device__ __forceinline__ float bflo(unsigned v){ return __uint_as_float(v << 16); }
static __device__ __forceinline__ float bfhi(unsigned v){ return __uint_as_float(v & 0xffff0000u); }

// ---------------------------------------------------------------------------
// Kernel B: node pre-pass.  f = fctp(x, W_lin1)*attr/sqrt(32) -> bf16.
// fbf layout (interleaved): fbf[n*128 + 4*u + {0,1,2,3}] = f0[u], f1[u][0..2]
// so the edge gather is ONE dwordx2 per (edge,lane).
// ---------------------------------------------------------------------------
__global__ __launch_bounds__(256) void node_pre_kernel(
    const float* __restrict__ node_input, const float* __restrict__ node_attr,
    const float* __restrict__ Wl0,  const float* __restrict__ Wl1,
    __hip_bfloat16* __restrict__ fbf)
{
    __shared__ float w_l0[1024], w_l1[1024];
    __shared__ float xs[8 * 128];
    int t = threadIdx.x;
    for (int i = t; i < 1024; i += 256) { w_l0[i] = Wl0[i]; w_l1[i] = Wl1[i]; }
    int base = blockIdx.x * 8;
    for (int i = t; i < 1024; i += 256) xs[i] = node_input[(size_t)base * 128 + i];
    __syncthreads();

    int nl = t >> 5, w = t & 31;
    int n = base + nl;
    const float* xr = &xs[nl * 128];
    float f0 = 0.f, f1[3] = {0.f, 0.f, 0.f};
    #pragma unroll
    for (int u = 0; u < 32; ++u) {
        float wl0 = w_l0[u * 32 + w], wl1 = w_l1[u * 32 + w];
        f0 += xr[u] * wl0;
        #pragma unroll
        for (int m = 0; m < 3; ++m) f1[m] += xr[32 + u * 3 + m] * wl1;
    }
    float as = node_attr[n] * S32;
    unsigned p0 = (unsigned)f2bf(f0 * as)    | ((unsigned)f2bf(f1[0] * as) << 16);
    unsigned p1 = (unsigned)f2bf(f1[1] * as) | ((unsigned)f2bf(f1[2] * as) << 16);
    *(uint2*)((unsigned short*)fbf + (size_t)n * 128 + 4 * w) = make_uint2(p0, p1);
}

// ---------------------------------------------------------------------------
// Kernel C: fused edge pass, MFMA MLP.  One wave = 16 edges per iteration.
//  GEMM1: z[16e x 64] = es[16e x 16] @ W_fc1 (K padded to 32) -> 4 MFMA
//  silu -> bf16 -> h_lds[16][72] (transpose handoff)
//  GEMM2: w[16e x 128] = h @ W_fc2 (K=64) -> 16 MFMA, scale folded in B-frags
//  w_lds interleaved [e][u][{wA,wB,wC,wD}] -> features read 1 ds_read_b128
//  mid row (256), eB/eC m-major: [0:32]=eA[u], [32:64]=eD[u],
//    [64+32m+u]=eB[m][u], [160+32m+u]=eC[m][u]  -> 4 affine atomics/lane/edge
// ---------------------------------------------------------------------------
__global__ __launch_bounds__(256) void edge_kernel(
    const float* __restrict__ es_g, const float* __restrict__ edge_attr,
    const int* __restrict__ esrc, const int* __restrict__ edst,
    const float* __restrict__ Wfc1, const float* __restrict__ Wfc2,
    const __hip_bfloat16* __restrict__ fbf, float* __restrict__ mid)
{
    __shared__ __align__(16) unsigned short h_lds[4][16 * 72];
    __shared__ __align__(16) float          w_lds[4][16 * 128];

    int t = threadIdx.x, wv = t >> 6, j = t & 63;
    int q = j >> 4, r = j & 15;
    int u31 = j & 31;

    // ---- loop-invariant B fragments (bf16, per-lane) ----
    // B layout for mfma_f32_16x16x32_bf16: lane holds B[k=8q+i][col=16t+r]
    bf16x8 b1[4];
    #pragma unroll
    for (int tt = 0; tt < 4; ++tt) {
        #pragma unroll
        for (int i = 0; i < 8; ++i) {
            int k = 8 * q + i;
            float v = (k < 16) ? Wfc1[k * 64 + 16 * tt + r] * 0.25f : 0.0f;  // fold 1/sqrt(16)
            b1[tt][i] = (short)f2bf(v);
        }
    }
    bf16x8 b2[8][2];
    #pragma unroll
    for (int tt = 0; tt < 8; ++tt)
        #pragma unroll
        for (int ks = 0; ks < 2; ++ks)
            #pragma unroll
            for (int i = 0; i < 8; ++i)
                b2[tt][ks][i] = (short)f2bf(Wfc2[(32 * ks + 8 * q + i) * 128 + 16 * tt + r] * WSCALE);

    unsigned short* hl = h_lds[wv];
    float*          wl = w_lds[wv];

    int  waveId = blockIdx.x * 4 + wv;
    long stride = (long)NBLK_E * 4 * 16;

    for (long e0 = (long)waveId * 16; e0 < N_EDGES; e0 += stride) {
        int sv = esrc[e0 + r];   // lanes r, r+16, r+32, r+48 hold edge e0+r
        int dv = edst[e0 + r];

        // ---- GEMM1: A = es rows (row=r, k=8q+i; zero for k>=16) ----
        bf16x8 a1;
        #pragma unroll
        for (int i = 0; i < 8; ++i) a1[i] = 0;
        if (q < 2) {
            const float* ep = es_g + (e0 + r) * 16 + 8 * q;
            float4 x0 = *(const float4*)ep;
            float4 x1 = *(const float4*)(ep + 4);
            a1[0] = (short)f2bf(x0.x); a1[1] = (short)f2bf(x0.y);
            a1[2] = (short)f2bf(x0.z); a1[3] = (short)f2bf(x0.w);
            a1[4] = (short)f2bf(x1.x); a1[5] = (short)f2bf(x1.y);
            a1[6] = (short)f2bf(x1.z); a1[7] = (short)f2bf(x1.w);
        }
        f32x4 zero4 = {0.f, 0.f, 0.f, 0.f};
        f32x4 acc1[4];
        #pragma unroll
        for (int tt = 0; tt < 4; ++tt)
            acc1[tt] = __builtin_amdgcn_mfma_f32_16x16x32_bf16(a1, b1[tt], zero4, 0, 0, 0);

        // ---- silu -> bf16 -> h_lds[edge=4q+rr][col=16tt+r] ----
        #pragma unroll
        for (int tt = 0; tt < 4; ++tt)
            #pragma unroll
            for (int rr = 0; rr < 4; ++rr) {
                float z = acc1[tt][rr];
                float h = z / (1.0f + __expf(-z));
                hl[(4 * q + rr) * 72 + 16 * tt + r] = f2bf(h);
            }

        // ---- GEMM2: A = h rows (row=r, k=8q+i + 32ks) ----
        bf16x8 a2_0 = *reinterpret_cast<const bf16x8*>(hl + r * 72 + 8 * q);
        bf16x8 a2_1 = *reinterpret_cast<const bf16x8*>(hl + r * 72 + 8 * q + 32);
        f32x4 acc2[8];
        #pragma unroll
        for (int tt = 0; tt < 8; ++tt) {
            acc2[tt] = __builtin_amdgcn_mfma_f32_16x16x32_bf16(a2_0, b2[tt][0], zero4, 0, 0, 0);
            acc2[tt] = __builtin_amdgcn_mfma_f32_16x16x32_bf16(a2_1, b2[tt][1], acc2[tt], 0, 0, 0);
        }

        // ---- w -> w_lds interleaved [e][u][comp]; c=16tt+r: comp=tt>>1, u=16(tt&1)+r
        #pragma unroll
        for (int tt = 0; tt < 8; ++tt)
            #pragma unroll
            for (int rr = 0; rr < 4; ++rr)
                wl[(4 * q + rr) * 128 + (16 * (tt & 1) + r) * 4 + (tt >> 1)] = acc2[tt][rr];

        // ---- features + atomic scatter: 4 atomics per lane per edge ----
        #pragma unroll 4
        for (int e = 0; e < 16; ++e) {
            int se = __shfl(sv, e);
            int de = __shfl(dv, e);
            float4 ea = ((const float4*)edge_attr)[e0 + e];   // y0, y1x, y1y, y1z
            uint2 gv = *(const uint2*)((const unsigned short*)fbf + (size_t)se * 128 + 4 * u31);
            f32x4 w4 = *reinterpret_cast<const f32x4*>(wl + e * 128 + u31 * 4);
            float g0  = bflo(gv.x), g1x = bfhi(gv.x);
            float g1y = bflo(gv.y), g1z = bfhi(gv.y);
            float wA = w4[0], wB = w4[1], wC = w4[2], wD = w4[3];
            bool lo = (j < 32);
            float wBg0 = wB * g0;
            float wCy0 = wC * ea.x;
            float dotD = g1x * ea.y + g1y * ea.z + g1z * ea.w;
            float v1 = lo ? wA * g0 * ea.x : wD * dotD * INV_SQRT3;
            float v2 = wBg0 * (lo ? ea.y : ea.z);
            float v3 = lo ? wBg0 * ea.w : wCy0 * g1x;
            float v4 = wCy0 * (lo ? g1y : g1z);
            float* mrow = mid + (size_t)de * 256;
            unsafeAtomicAdd(mrow + j,        v1);
            unsafeAtomicAdd(mrow + 64 + j,   v2);
            unsafeAtomicAdd(mrow + 128 + j,  v3);
            unsafeAtomicAdd(mrow + 192 + j,  v4);
        }
    }
}

// ---------------------------------------------------------------------------
// Kernel D: node post-pass (adapted to m-major eB/eC mid layout).
// ---------------------------------------------------------------------------
__global__ __launch_bounds__(256) void node_post_kernel(
    const float* __restrict__ mid, const float* __restrict__ node_input,
    const float* __restrict__ node_attr,
    const float* __restrict__ Wsc0, const float* __restrict__ Wsc1,
    const float* __restrict__ W20, const float* __restrict__ W21,
    const float* __restrict__ W3, float* __restrict__ out)
{
    __shared__ float w20[2048], w21[2048], w3[64];
    __shared__ float wsc0[1024], wsc1[1024];
    __shared__ float ms[8 * 256];
    __shared__ float xs[8 * 128];
    int t = threadIdx.x;
    for (int i = t; i < 2048; i += 256) { w20[i] = W20[i]; w21[i] = W21[i]; }
    for (int i = t; i < 1024; i += 256) { wsc0[i] = Wsc0[i]; wsc1[i] = Wsc1[i]; }
    if (t < 64) w3[t] = W3[t];
    int base = blockIdx.x * 8;
    for (int i = t; i < 2048; i += 256) ms[i] = mid[(size_t)base * 256 + i];
    for (int i = t; i < 1024; i += 256) xs[i] = node_input[(size_t)base * 128 + i];
    __syncthreads();

    int nl = t >> 5, w = t & 31;
    int n = base + nl;
    const float* mr = &ms[nl * 256];
    const float* xr = &xs[nl * 128];

    // recompute sc (f32)
    float s0 = 0.f, s1[3] = {0.f, 0.f, 0.f};
    #pragma unroll
    for (int u = 0; u < 32; ++u) {
        float ws = wsc0[u * 32 + w], ws1 = wsc1[u * 32 + w];
        s0 += xr[u] * ws;
        #pragma unroll
        for (int m = 0; m < 3; ++m) s1[m] += xr[32 + u * 3 + m] * ws1;
    }

    // conv = lin2(mid), angle   (mid: A[u], D[32+u], eB m-major 64+32m+u, eC 160+32m+u)
    float o0 = 0.f, ang = 0.f, o1[3] = {0.f, 0.f, 0.f};
    #pragma unroll
    for (int u = 0; u < 32; ++u) {
        float mA = mr[u], mD = mr[32 + u];
        o0  += mA * w20[u * 32 + w] + mD * w20[(32 + u) * 32 + w];
        ang += mA * w3[u] + mD * w3[32 + u];
        float wBu = w21[u * 32 + w], wCu = w21[(32 + u) * 32 + w];
        o1[0] += mr[64 + u]  * wBu + mr[160 + u] * wCu;
        o1[1] += mr[96 + u]  * wBu + mr[192 + u] * wCu;
        o1[2] += mr[128 + u] * wBu + mr[224 + u] * wCu;
    }
    float attr = node_attr[n];
    float a8 = attr * 0.125f;
    float as = attr * S32;
    float angle = 0.1f * ang * a8;
    float cs = cosf(angle), sn = sinf(angle);

    out[(size_t)n * 128 + w] = cs * (s0 * as) + sn * (o0 * a8);
    #pragma unroll
    for (int m = 0; m < 3; ++m)
        out[(size_t)n * 128 + 32 + w * 3 + m] = cs * (s1[m] * as) + sn * (o1[m] * a8);
}

// ---------------------------------------------------------------------------
extern "C" void kernel_launch(void* const* d_in, const int* in_sizes, int n_in,
                              void* d_out, int out_size, void* d_ws, size_t ws_size,
                              hipStream_t stream) {
    const float* node_input   = (const float*)d_in[0];
    const float* node_attr    = (const float*)d_in[1];
    const int*   edge_src     = (const int*)d_in[2];
    const int*   edge_dst     = (const int*)d_in[3];
    const float* edge_attr    = (const float*)d_in[4];
    const float* edge_scalars = (const float*)d_in[5];
    const float* W_sc0    = (const float*)d_in[6];
    const float* W_sc1    = (const float*)d_in[7];
    const float* W_lin1_0 = (const float*)d_in[8];
    const float* W_lin1_1 = (const float*)d_in[9];
    const float* W_fc1    = (const float*)d_in[10];
    const float* W_fc2    = (const float*)d_in[11];
    const float* W_lin2_0 = (const float*)d_in[12];
    const float* W_lin2_1 = (const float*)d_in[13];
    const float* W_lin3   = (const float*)d_in[14];
    float* out = (float*)d_out;

    // Workspace: mid (N*256 f32 = 51.2 MB) in d_ws.
    // fbf (bf16, 12.8 MB) in the first half of d_out (dead before post pass).
    float*          mid = (float*)d_ws;
    __hip_bfloat16* fbf = (__hip_bfloat16*)d_out;

    hipMemsetAsync(mid, 0, (size_t)N_NODES * 256 * 4, stream);
    node_pre_kernel<<<N_NODES / 8, 256, 0, stream>>>(
        node_input, node_attr, W_lin1_0, W_lin1_1, fbf);
    edge_kernel<<<NBLK_E, 256, 0, stream>>>(
        edge_scalars, edge_attr, edge_src, edge_dst, W_fc1, W_fc2, fbf, mid);
    node_post_kernel<<<N_NODES / 8, 256, 0, stream>>>(
        mid, node_input, node_attr, W_sc0, W_sc1, W_lin2_0, W_lin2_1, W_lin3, out);
}

// Round 12
// 452.435 us; speedup vs baseline: 1.9574x; 1.9574x over previous
//
#include <hip/hip_runtime.h>
#include <hip/hip_bf16.h>
#include <hip/hip_fp16.h>

#define N_NODES 50000
#define N_EDGES 500000
#define NBLK_E  1024
#define CW      132           // halves per conv row (128 data + angle + pad)
#define FBF_OFF (16u * 1024u * 1024u)   // fbf offset inside d_ws (conv is 13.2MB)

// scales
#define S32        0.17677669529663687f   // 1/sqrt(32)
#define INV_SQRT3  0.5773502691896258f
#define WSCALE     0.03952847075210474f   // (1/sqrt(64)) * (1/sqrt(10))

typedef __attribute__((ext_vector_type(8))) short bf16x8;
typedef __attribute__((ext_vector_type(4))) float f32x4;

static __device__ __forceinline__ unsigned short f2bf(float x) {
    __hip_bfloat16 b = __float2bfloat16(x);
    union { __hip_bfloat16 b; unsigned short u; } cv; cv.b = b; return cv.u;
}
static __device__ __forceinline__ float bflo(unsigned v){ return __uint_as_float(v << 16); }
static __device__ __forceinline__ float bfhi(unsigned v){ return __uint_as_float(v & 0xffff0000u); }

// ---------------------------------------------------------------------------
// Kernel B: node pre-pass.  f = fctp(x, W_lin1)*attr/sqrt(32) -> bf16.
// fbf layout (interleaved): fbf[n*128 + 4*u + {0,1,2,3}] = f0[u], f1[u][0..2]
// ---------------------------------------------------------------------------
__global__ __launch_bounds__(256) void node_pre_kernel(
    const float* __restrict__ node_input, const float* __restrict__ node_attr,
    const float* __restrict__ Wl0,  const float* __restrict__ Wl1,
    __hip_bfloat16* __restrict__ fbf)
{
    __shared__ float w_l0[1024], w_l1[1024];
    __shared__ float xs[8 * 128];
    int t = threadIdx.x;
    for (int i = t; i < 1024; i += 256) { w_l0[i] = Wl0[i]; w_l1[i] = Wl1[i]; }
    int base = blockIdx.x * 8;
    for (int i = t; i < 1024; i += 256) xs[i] = node_input[(size_t)base * 128 + i];
    __syncthreads();

    int nl = t >> 5, w = t & 31;
    int n = base + nl;
    const float* xr = &xs[nl * 128];
    float f0 = 0.f, f1[3] = {0.f, 0.f, 0.f};
    #pragma unroll
    for (int u = 0; u < 32; ++u) {
        float wl0 = w_l0[u * 32 + w], wl1 = w_l1[u * 32 + w];
        f0 += xr[u] * wl0;
        #pragma unroll
        for (int m = 0; m < 3; ++m) f1[m] += xr[32 + u * 3 + m] * wl1;
    }
    float as = node_attr[n] * S32;
    unsigned p0 = (unsigned)f2bf(f0 * as)    | ((unsigned)f2bf(f1[0] * as) << 16);
    unsigned p1 = (unsigned)f2bf(f1[1] * as) | ((unsigned)f2bf(f1[2] * as) << 16);
    *(uint2*)((unsigned short*)fbf + (size_t)n * 128 + 4 * w) = make_uint2(p0, p1);
}

// ---------------------------------------------------------------------------
// Kernel C: fused edge pass with lin2/lin3 folded in.  One wave = 16 edges.
//  GEMM1 (4 MFMA) -> silu -> h ; GEMM2 (16 MFMA) -> w_lds [e][u][{A,B,C,D}]
//  features -> featL bf16 [e][264] ; fold GEMMs (18 MFMA) -> o0/o1m/angle
//  scatter: pk_add_f16 into conv rows (CW=132): block b=0..3 {o0,o1m0..2}:
//    halves (b*32+2r, b*32+2r+1) = cols (r, 16+r); angle at half 128.
// ---------------------------------------------------------------------------
__global__ __launch_bounds__(256) void edge_kernel(
    const float* __restrict__ es_g, const float* __restrict__ edge_attr,
    const int* __restrict__ esrc, const int* __restrict__ edst,
    const float* __restrict__ Wfc1, const float* __restrict__ Wfc2,
    const float* __restrict__ W20, const float* __restrict__ W21,
    const float* __restrict__ W3,
    const __hip_bfloat16* __restrict__ fbf, __half* __restrict__ conv)
{
    __shared__ __align__(16) unsigned short featL[4][16 * 264];  // 33792 B
    __shared__ __align__(16) float          w_lds[4][16 * 128];  // 32768 B
    __shared__ __align__(16) unsigned short WfL[5120];           // 10240 B

    int t = threadIdx.x, wv = t >> 6, j = t & 63;
    int q = j >> 4, r = j & 15;
    int u31 = j & 31;

    // ---- fold-weight LDS image: [T][ks][r][q][i], T: 0,1=W20 2=0.1*W3 3,4=W21
    for (int idx = t; idx < 5120; idx += 256) {
        int i  = idx & 7;
        int qq = (idx >> 3) & 3;
        int rr = (idx >> 5) & 15;
        int ks = (idx >> 9) & 1;
        int T  = idx >> 10;
        int k  = 32 * ks + 8 * qq + i;
        float v;
        if (T < 2)       v = W20[k * 32 + 16 * T + rr];
        else if (T == 2) v = (rr == 0) ? 0.1f * W3[k] : 0.0f;
        else             v = W21[k * 32 + 16 * (T - 3) + rr];
        WfL[idx] = f2bf(v);
    }

    // ---- loop-invariant MLP B fragments (registers) ----
    bf16x8 b1[4];
    #pragma unroll
    for (int tt = 0; tt < 4; ++tt) {
        #pragma unroll
        for (int i = 0; i < 8; ++i) {
            int k = 8 * q + i;
            float v = (k < 16) ? Wfc1[k * 64 + 16 * tt + r] * 0.25f : 0.0f;
            b1[tt][i] = (short)f2bf(v);
        }
    }
    bf16x8 b2[8][2];
    #pragma unroll
    for (int tt = 0; tt < 8; ++tt)
        #pragma unroll
        for (int ks = 0; ks < 2; ++ks)
            #pragma unroll
            for (int i = 0; i < 8; ++i)
                b2[tt][ks][i] = (short)f2bf(Wfc2[(32 * ks + 8 * q + i) * 128 + 16 * tt + r] * WSCALE);

    __syncthreads();   // WfL ready

    unsigned short* fl = featL[wv];
    float*          wl = w_lds[wv];

    int  waveId = blockIdx.x * 4 + wv;
    long stride = (long)NBLK_E * 4 * 16;

    for (long e0 = (long)waveId * 16; e0 < N_EDGES; e0 += stride) {
        int sv = esrc[e0 + r];
        int dv = edst[e0 + r];

        // ---- GEMM1 ----
        bf16x8 a1;
        #pragma unroll
        for (int i = 0; i < 8; ++i) a1[i] = 0;
        if (q < 2) {
            const float* ep = es_g + (e0 + r) * 16 + 8 * q;
            float4 x0 = *(const float4*)ep;
            float4 x1 = *(const float4*)(ep + 4);
            a1[0] = (short)f2bf(x0.x); a1[1] = (short)f2bf(x0.y);
            a1[2] = (short)f2bf(x0.z); a1[3] = (short)f2bf(x0.w);
            a1[4] = (short)f2bf(x1.x); a1[5] = (short)f2bf(x1.y);
            a1[6] = (short)f2bf(x1.z); a1[7] = (short)f2bf(x1.w);
        }
        f32x4 zero4 = {0.f, 0.f, 0.f, 0.f};
        f32x4 acc1[4];
        #pragma unroll
        for (int tt = 0; tt < 4; ++tt)
            acc1[tt] = __builtin_amdgcn_mfma_f32_16x16x32_bf16(a1, b1[tt], zero4, 0, 0, 0);

        // ---- silu -> h (rows stride 72 inside featL; consumed before feat writes) ----
        #pragma unroll
        for (int tt = 0; tt < 4; ++tt)
            #pragma unroll
            for (int rr = 0; rr < 4; ++rr) {
                float z = acc1[tt][rr];
                float h = z / (1.0f + __expf(-z));
                fl[(4 * q + rr) * 72 + 16 * tt + r] = f2bf(h);
            }

        // ---- GEMM2 ----
        bf16x8 a2_0 = *reinterpret_cast<const bf16x8*>(fl + r * 72 + 8 * q);
        bf16x8 a2_1 = *reinterpret_cast<const bf16x8*>(fl + r * 72 + 8 * q + 32);
        f32x4 acc2[8];
        #pragma unroll
        for (int tt = 0; tt < 8; ++tt) {
            acc2[tt] = __builtin_amdgcn_mfma_f32_16x16x32_bf16(a2_0, b2[tt][0], zero4, 0, 0, 0);
            acc2[tt] = __builtin_amdgcn_mfma_f32_16x16x32_bf16(a2_1, b2[tt][1], acc2[tt], 0, 0, 0);
        }
        #pragma unroll
        for (int tt = 0; tt < 8; ++tt)
            #pragma unroll
            for (int rr = 0; rr < 4; ++rr)
                wl[(4 * q + rr) * 128 + (16 * (tt & 1) + r) * 4 + (tt >> 1)] = acc2[tt][rr];

        // ---- features -> featL (bf16) ----
        #pragma unroll 4
        for (int e = 0; e < 16; ++e) {
            int se = __shfl(sv, e);
            float4 ea = ((const float4*)edge_attr)[e0 + e];
            uint2 gv = *(const uint2*)((const unsigned short*)fbf + (size_t)se * 128 + 4 * u31);
            f32x4 w4 = *reinterpret_cast<const f32x4*>(wl + e * 128 + u31 * 4);
            float g0  = bflo(gv.x), g1x = bfhi(gv.x);
            float g1y = bflo(gv.y), g1z = bfhi(gv.y);
            unsigned short* fr = fl + e * 264;
            if (j < 32) {
                float wBg0 = w4[1] * g0;
                fr[u31]        = f2bf(w4[0] * g0 * ea.x);    // eA
                fr[64  + u31]  = f2bf(wBg0 * ea.y);          // eB m=0
                fr[96  + u31]  = f2bf(wBg0 * ea.z);          // eB m=1
                fr[128 + u31]  = f2bf(wBg0 * ea.w);          // eB m=2
            } else {
                float wCy0 = w4[2] * ea.x;
                float dotD = g1x * ea.y + g1y * ea.z + g1z * ea.w;
                fr[32  + u31]  = f2bf(w4[3] * dotD * INV_SQRT3);  // eD
                fr[160 + u31]  = f2bf(wCy0 * g1x);                // eC m=0
                fr[192 + u31]  = f2bf(wCy0 * g1y);                // eC m=1
                fr[224 + u31]  = f2bf(wCy0 * g1z);                // eC m=2
            }
        }

        // ---- fold GEMMs ----
        bf16x8 aA0 = *reinterpret_cast<const bf16x8*>(fl + r * 264 + 8 * q);
        bf16x8 aA1 = *reinterpret_cast<const bf16x8*>(fl + r * 264 + 32 + 8 * q);
        f32x4 accA[3];
        #pragma unroll
        for (int T = 0; T < 3; ++T) {
            const bf16x8 bf0 = *reinterpret_cast<const bf16x8*>(WfL + ((T * 2 + 0) * 16 + r) * 32 + q * 8);
            const bf16x8 bf1 = *reinterpret_cast<const bf16x8*>(WfL + ((T * 2 + 1) * 16 + r) * 32 + q * 8);
            accA[T] = __builtin_amdgcn_mfma_f32_16x16x32_bf16(aA0, bf0, zero4, 0, 0, 0);
            accA[T] = __builtin_amdgcn_mfma_f32_16x16x32_bf16(aA1, bf1, accA[T], 0, 0, 0);
        }
        bf16x8 bB[2][2];
        #pragma unroll
        for (int tt = 0; tt < 2; ++tt)
            #pragma unroll
            for (int ks = 0; ks < 2; ++ks)
                bB[tt][ks] = *reinterpret_cast<const bf16x8*>(WfL + (((3 + tt) * 2 + ks) * 16 + r) * 32 + q * 8);
        f32x4 accB[3][2];
        #pragma unroll
        for (int m = 0; m < 3; ++m) {
            bf16x8 aB0 = *reinterpret_cast<const bf16x8*>(fl + r * 264 + 64  + 32 * m + 8 * q);
            bf16x8 aB1 = *reinterpret_cast<const bf16x8*>(fl + r * 264 + 160 + 32 * m + 8 * q);
            #pragma unroll
            for (int tt = 0; tt < 2; ++tt) {
                accB[m][tt] = __builtin_amdgcn_mfma_f32_16x16x32_bf16(aB0, bB[tt][0], zero4, 0, 0, 0);
                accB[m][tt] = __builtin_amdgcn_mfma_f32_16x16x32_bf16(aB1, bB[tt][1], accB[m][tt], 0, 0, 0);
            }
        }

        // ---- pk_f16 atomic scatter ----
        #pragma unroll
        for (int rr = 0; rr < 4; ++rr) {
            int de = __shfl(dv, 4 * q + rr);
            __half* crow = conv + (size_t)de * CW;
            __half2 v0 = __halves2half2(__float2half(accA[0][rr]), __float2half(accA[1][rr]));
            unsafeAtomicAdd((__half2*)(crow + 2 * r), v0);
            #pragma unroll
            for (int m = 0; m < 3; ++m) {
                __half2 vm = __halves2half2(__float2half(accB[m][0][rr]), __float2half(accB[m][1][rr]));
                unsafeAtomicAdd((__half2*)(crow + 32 * (1 + m) + 2 * r), vm);
            }
            if (r == 0) {
                __half2 va = __halves2half2(__float2half(accA[2][rr]), __float2half(0.0f));
                unsafeAtomicAdd((__half2*)(crow + 128), va);
            }
        }
    }
}

// ---------------------------------------------------------------------------
// Kernel D: node post-pass. sc recompute (f32) + decode folded conv + blend.
// ---------------------------------------------------------------------------
__global__ __launch_bounds__(256) void node_post_kernel(
    const __half* __restrict__ conv, const float* __restrict__ node_input,
    const float* __restrict__ node_attr,
    const float* __restrict__ Wsc0, const float* __restrict__ Wsc1,
    float* __restrict__ out)
{
    __shared__ float wsc0[1024], wsc1[1024];
    __shared__ float xs[8 * 128];
    __shared__ unsigned cs32[8 * 66];
    int t = threadIdx.x;
    for (int i = t; i < 1024; i += 256) { wsc0[i] = Wsc0[i]; wsc1[i] = Wsc1[i]; }
    int base = blockIdx.x * 8;
    for (int i = t; i < 1024; i += 256) xs[i] = node_input[(size_t)base * 128 + i];
    for (int i = t; i < 528; i += 256)  cs32[i] = ((const unsigned*)conv)[(size_t)base * 66 + i];
    __syncthreads();

    int nl = t >> 5, w = t & 31;
    int n = base + nl;
    const float* xr = &xs[nl * 128];
    const __half* ch = (const __half*)cs32 + nl * CW;

    float s0 = 0.f, s1[3] = {0.f, 0.f, 0.f};
    #pragma unroll
    for (int u = 0; u < 32; ++u) {
        float ws = wsc0[u * 32 + w], ws1 = wsc1[u * 32 + w];
        s0 += xr[u] * ws;
        #pragma unroll
        for (int m = 0; m < 3; ++m) s1[m] += xr[32 + u * 3 + m] * ws1;
    }

    float attr = node_attr[n];
    float a8 = attr * 0.125f;
    float as = attr * S32;

    int p0 = (w < 16) ? 2 * w : 2 * (w - 16) + 1;
    float o0  = __half2float(ch[p0]) * a8;
    float o1m[3];
    #pragma unroll
    for (int m = 0; m < 3; ++m) o1m[m] = __half2float(ch[32 * (1 + m) + p0]) * a8;
    float angle = __half2float(ch[128]) * a8;   // 0.1 folded into WfL
    float csn = cosf(angle), sn = sinf(angle);

    out[(size_t)n * 128 + w] = csn * (s0 * as) + sn * o0;
    #pragma unroll
    for (int m = 0; m < 3; ++m)
        out[(size_t)n * 128 + 32 + w * 3 + m] = csn * (s1[m] * as) + sn * o1m[m];
}

// ---------------------------------------------------------------------------
extern "C" void kernel_launch(void* const* d_in, const int* in_sizes, int n_in,
                              void* d_out, int out_size, void* d_ws, size_t ws_size,
                              hipStream_t stream) {
    const float* node_input   = (const float*)d_in[0];
    const float* node_attr    = (const float*)d_in[1];
    const int*   edge_src     = (const int*)d_in[2];
    const int*   edge_dst     = (const int*)d_in[3];
    const float* edge_attr    = (const float*)d_in[4];
    const float* edge_scalars = (const float*)d_in[5];
    const float* W_sc0    = (const float*)d_in[6];
    const float* W_sc1    = (const float*)d_in[7];
    const float* W_lin1_0 = (const float*)d_in[8];
    const float* W_lin1_1 = (const float*)d_in[9];
    const float* W_fc1    = (const float*)d_in[10];
    const float* W_fc2    = (const float*)d_in[11];
    const float* W_lin2_0 = (const float*)d_in[12];
    const float* W_lin2_1 = (const float*)d_in[13];
    const float* W_lin3   = (const float*)d_in[14];
    float* out = (float*)d_out;

    // ALL scratch in d_ws (d_out is write-once, by the post kernel only):
    //   conv @ +0       : N*132 halves = 13.2 MB (zeroed each call)
    //   fbf  @ +16 MB   : N*128 bf16   = 12.8 MB (fully overwritten each call)
    // Total 28.8 MB; ws_size >= 51.2 MB proven in rounds 6/8.
    __half*         conv = (__half*)d_ws;
    __hip_bfloat16* fbf  = (__hip_bfloat16*)((char*)d_ws + FBF_OFF);

    hipMemsetAsync(conv, 0, (size_t)N_NODES * CW * 2, stream);
    node_pre_kernel<<<N_NODES / 8, 256, 0, stream>>>(
        node_input, node_attr, W_lin1_0, W_lin1_1, fbf);
    edge_kernel<<<NBLK_E, 256, 0, stream>>>(
        edge_scalars, edge_attr, edge_src, edge_dst, W_fc1, W_fc2,
        W_lin2_0, W_lin2_1, W_lin3, fbf, conv);
    node_post_kernel<<<N_NODES / 8, 256, 0, stream>>>(
        conv, node_input, node_attr, W_sc0, W_sc1, out);
}